// Round 2
// baseline (262.181 us; speedup 1.0000x reference)
//
#include <hip/hip_runtime.h>
#include <hip/hip_bf16.h>
#include <stdint.h>

// out = X @ W^T + 0.01*(|X| @ |W|^T) - 1e-6, all 4096x4096, fp32 in/out.
// Main GEMM: bf16 mfma_f32_32x32x16. Abs GEMM: i8 mfma_i32_32x32x32 with
// fixed scales (error budget is 100x since result is scaled by 0.01).
// Fallback (small ws): abs path via in-register AND of the bf16 fragments.

#define NDIM 4096
#define KDIM 4096

typedef __attribute__((ext_vector_type(8))) __bf16 bf16x8;
typedef __attribute__((ext_vector_type(8))) unsigned short u16x8;
typedef __attribute__((ext_vector_type(8))) char c8x8;
typedef __attribute__((ext_vector_type(4))) int i32x4;
typedef __attribute__((ext_vector_type(16))) int i32x16;
typedef __attribute__((ext_vector_type(16))) float f32x16;

#define QSX 16.0f    // |x| quant scale (|x|max ~5.5 -> q<=88)
#define QSW 128.0f   // |w| quant scale (|w|max ~0.55 -> q<=70)
#define ABS_SCALE (0.01f / (16.0f * 128.0f))  // 0.01 / (QSX*QSW)

// ---------------- fp32 -> bf16 (RNE) [+ optional |.| -> i8] ----------------
template <bool Q>
__global__ __launch_bounds__(256) void conv_kernel(
    const float* __restrict__ src, unsigned short* __restrict__ bd,
    signed char* __restrict__ qd, float qscale, int n8) {
  int i = blockIdx.x * 256 + threadIdx.x;
  if (i >= n8) return;
  const float4* sp = reinterpret_cast<const float4*>(src) + (size_t)i * 2;
  float4 a = sp[0];
  float4 b = sp[1];
  float v[8] = {a.x, a.y, a.z, a.w, b.x, b.y, b.z, b.w};
  u16x8 r;
  c8x8 q;
#pragma unroll
  for (int j = 0; j < 8; ++j) {
    uint32_t u = __builtin_bit_cast(uint32_t, v[j]);
    u += 0x7FFFu + ((u >> 16) & 1u);  // round-to-nearest-even
    r[j] = (unsigned short)(u >> 16);
    if (Q) {
      int qi = (int)(fabsf(v[j]) * qscale + 0.5f);
      q[j] = (char)(qi > 127 ? 127 : qi);
    }
  }
  *reinterpret_cast<u16x8*>(bd + (size_t)i * 8) = r;
  if (Q) *reinterpret_cast<c8x8*>(qd + (size_t)i * 8) = q;
}

// ---------------- dual GEMM, tile 128x128, BK=64, 8 waves (2Mx4N) ----------
// Wave tile 64x32 -> 2 M-frags x 1 N-frag of 32x32. LDS rows are 128B with
// 16B-granule XOR swizzle g^(row&7) (pre-swizzled global source; reads apply
// the same XOR) -> conflict-free. i8 tiles packed as 128B rows = 2 K-tiles.
template <bool USE_I8>
__global__ __launch_bounds__(512, 2) void gemm_dual_kernel(
    const unsigned short* __restrict__ Xb, const unsigned short* __restrict__ Wb,
    const signed char* __restrict__ Xq, const signed char* __restrict__ Wq,
    float* __restrict__ out) {
  __shared__ alignas(16) unsigned short As[128 * 64];
  __shared__ alignas(16) unsigned short Bs[128 * 64];
  __shared__ alignas(16) unsigned char As8[USE_I8 ? 128 * 128 : 16];
  __shared__ alignas(16) unsigned char Bs8[USE_I8 ? 128 * 128 : 16];

  const int tid = threadIdx.x;
  const int l = tid & 63;
  const int w = tid >> 6;  // wave 0..7
  const int wr = w >> 2;   // 0..1  (M)
  const int wc = w & 3;    // 0..3  (N)

  const int bm = blockIdx.x & 31;
  const int bn = blockIdx.x >> 5;
  const int row0 = bm << 7;
  const int col0 = bn << 7;

  // --- bf16 staging: wave w stages rows {8w..8w+7} and {64+8w..} ---
  const int rsub = (w << 3) + (l >> 3);
  const int gsrc = (l & 7) ^ (l >> 3);  // swizzled source granule (16B units)
  const unsigned short* aSrc = Xb + (size_t)(row0 + rsub) * KDIM + gsrc * 8;
  const unsigned short* bSrc = Wb + (size_t)(col0 + rsub) * KDIM + gsrc * 8;
  unsigned short* aDst0 = As + w * 512;
  unsigned short* bDst0 = Bs + w * 512;

  // --- i8 staging (byte addressed, rows are 128B covering 2 K-tiles) ---
  const signed char* a8Src = Xq + (size_t)(row0 + rsub) * KDIM + gsrc * 16;
  const signed char* b8Src = Wq + (size_t)(col0 + rsub) * KDIM + gsrc * 16;
  unsigned char* a8Dst0 = As8 + w * 1024;
  unsigned char* b8Dst0 = Bs8 + w * 1024;

  // --- fragment read coords ---
  const int lr = l & 31;   // row-within-32 / out col
  const int hi = l >> 5;   // k-half
  const int sw = lr & 7;   // row swizzle bits
  const int rowA0 = ((wr << 6) + lr) * 64;        // elements
  const int rowA1 = ((wr << 6) + 32 + lr) * 64;
  const int rowB = ((wc << 5) + lr) * 64;
  const int rowA80 = ((wr << 6) + lr) * 128;      // bytes
  const int rowA81 = ((wr << 6) + 32 + lr) * 128;
  const int rowB8 = ((wc << 5) + lr) * 128;

  f32x16 accS[2];
  f32x16 accA[2];
  i32x16 accI[2];
#pragma unroll
  for (int m = 0; m < 2; ++m) {
    accS[m] = (f32x16)0.0f;
    accA[m] = (f32x16)0.0f;
    accI[m] = (i32x16)0;
  }

  for (int kt = 0; kt < KDIM / 64; ++kt) {
    {
      const unsigned short* ap = aSrc + kt * 64;
      const unsigned short* bp = bSrc + kt * 64;
      __builtin_amdgcn_global_load_lds(
          (const __attribute__((address_space(1))) void*)ap,
          (__attribute__((address_space(3))) void*)aDst0, 16, 0, 0);
      __builtin_amdgcn_global_load_lds(
          (const __attribute__((address_space(1))) void*)(ap + (size_t)64 * KDIM),
          (__attribute__((address_space(3))) void*)(aDst0 + 4096), 16, 0, 0);
      __builtin_amdgcn_global_load_lds(
          (const __attribute__((address_space(1))) void*)bp,
          (__attribute__((address_space(3))) void*)bDst0, 16, 0, 0);
      __builtin_amdgcn_global_load_lds(
          (const __attribute__((address_space(1))) void*)(bp + (size_t)64 * KDIM),
          (__attribute__((address_space(3))) void*)(bDst0 + 4096), 16, 0, 0);
      if (USE_I8 && (kt & 1) == 0) {
        const signed char* a8p = a8Src + (kt >> 1) * 128;
        const signed char* b8p = b8Src + (kt >> 1) * 128;
        __builtin_amdgcn_global_load_lds(
            (const __attribute__((address_space(1))) void*)a8p,
            (__attribute__((address_space(3))) void*)a8Dst0, 16, 0, 0);
        __builtin_amdgcn_global_load_lds(
            (const __attribute__((address_space(1))) void*)(a8p + (size_t)64 * KDIM),
            (__attribute__((address_space(3))) void*)(a8Dst0 + 8192), 16, 0, 0);
        __builtin_amdgcn_global_load_lds(
            (const __attribute__((address_space(1))) void*)b8p,
            (__attribute__((address_space(3))) void*)b8Dst0, 16, 0, 0);
        __builtin_amdgcn_global_load_lds(
            (const __attribute__((address_space(1))) void*)(b8p + (size_t)64 * KDIM),
            (__attribute__((address_space(3))) void*)(b8Dst0 + 8192), 16, 0, 0);
      }
    }
    __syncthreads();

    if constexpr (USE_I8) {
      const int p4 = (kt & 1) << 2;
#pragma unroll
      for (int kk8 = 0; kk8 < 2; ++kk8) {
        const int g = ((p4 + kk8 * 2 + hi) ^ sw) * 16;
        i32x4 a0 = *reinterpret_cast<const i32x4*>(As8 + rowA80 + g);
        i32x4 a1 = *reinterpret_cast<const i32x4*>(As8 + rowA81 + g);
        i32x4 b0 = *reinterpret_cast<const i32x4*>(Bs8 + rowB8 + g);
        accI[0] = __builtin_amdgcn_mfma_i32_32x32x32_i8(a0, b0, accI[0], 0, 0, 0);
        accI[1] = __builtin_amdgcn_mfma_i32_32x32x32_i8(a1, b0, accI[1], 0, 0, 0);
      }
    }

#pragma unroll
    for (int kk = 0; kk < 4; ++kk) {
      const int gE = ((kk * 2 + hi) ^ sw) * 8;  // elements
      i32x4 aR0 = *reinterpret_cast<const i32x4*>(As + rowA0 + gE);
      i32x4 aR1 = *reinterpret_cast<const i32x4*>(As + rowA1 + gE);
      i32x4 bR = *reinterpret_cast<const i32x4*>(Bs + rowB + gE);
      accS[0] = __builtin_amdgcn_mfma_f32_32x32x16_bf16(
          __builtin_bit_cast(bf16x8, aR0), __builtin_bit_cast(bf16x8, bR),
          accS[0], 0, 0, 0);
      accS[1] = __builtin_amdgcn_mfma_f32_32x32x16_bf16(
          __builtin_bit_cast(bf16x8, aR1), __builtin_bit_cast(bf16x8, bR),
          accS[1], 0, 0, 0);
      if constexpr (!USE_I8) {
        i32x4 aA0 = aR0 & 0x7FFF7FFF;
        i32x4 aA1 = aR1 & 0x7FFF7FFF;
        i32x4 bA = bR & 0x7FFF7FFF;
        accA[0] = __builtin_amdgcn_mfma_f32_32x32x16_bf16(
            __builtin_bit_cast(bf16x8, aA0), __builtin_bit_cast(bf16x8, bA),
            accA[0], 0, 0, 0);
        accA[1] = __builtin_amdgcn_mfma_f32_32x32x16_bf16(
            __builtin_bit_cast(bf16x8, aA1), __builtin_bit_cast(bf16x8, bA),
            accA[1], 0, 0, 0);
      }
    }
    __syncthreads();
  }

  // --- epilogue: C/D 32x32 layout col=lane&31, row=(j&3)+8*(j>>2)+4*hi ---
  const int ocol = col0 + (wc << 5) + lr;
#pragma unroll
  for (int m = 0; m < 2; ++m)
#pragma unroll
    for (int j = 0; j < 16; ++j) {
      int r = row0 + (wr << 6) + m * 32 + (j & 3) + 8 * (j >> 2) + 4 * hi;
      float bias;
      if constexpr (USE_I8)
        bias = ABS_SCALE * (float)accI[m][j];
      else
        bias = 0.01f * accA[m][j];
      out[(size_t)r * NDIM + ocol] = accS[m][j] + bias - 1e-6f;
    }
}

extern "C" void kernel_launch(void* const* d_in, const int* in_sizes, int n_in,
                              void* d_out, int out_size, void* d_ws, size_t ws_size,
                              hipStream_t stream) {
  const float* X = (const float*)d_in[0];
  const float* W = (const float*)d_in[1];
  float* out = (float*)d_out;
  const size_t NELEM = (size_t)NDIM * KDIM;
  unsigned short* Xb = (unsigned short*)d_ws;
  unsigned short* Wb = Xb + NELEM;
  signed char* Xq = (signed char*)(Wb + NELEM);
  signed char* Wq = Xq + NELEM;

  const int n8 = (int)(NELEM / 8);
  const int cblocks = n8 / 256;
  const bool use_i8 = ws_size >= NELEM * 6;  // bf16 x2 + i8 x2 = 6 B/elem

  if (use_i8) {
    hipLaunchKernelGGL(conv_kernel<true>, dim3(cblocks), dim3(256), 0, stream,
                       X, Xb, Xq, QSX, n8);
    hipLaunchKernelGGL(conv_kernel<true>, dim3(cblocks), dim3(256), 0, stream,
                       W, Wb, Wq, QSW, n8);
    hipLaunchKernelGGL(gemm_dual_kernel<true>, dim3(1024), dim3(512), 0, stream,
                       Xb, Wb, Xq, Wq, out);
  } else {
    hipLaunchKernelGGL(conv_kernel<false>, dim3(cblocks), dim3(256), 0, stream,
                       X, Xb, (signed char*)nullptr, QSX, n8);
    hipLaunchKernelGGL(conv_kernel<false>, dim3(cblocks), dim3(256), 0, stream,
                       W, Wb, (signed char*)nullptr, QSW, n8);
    hipLaunchKernelGGL(gemm_dual_kernel<false>, dim3(1024), dim3(512), 0, stream,
                       Xb, Wb, (signed char*)nullptr, (signed char*)nullptr, out);
  }
}

// Round 3
// 249.939 us; speedup vs baseline: 1.0490x; 1.0490x over previous
//
#include <hip/hip_runtime.h>
#include <hip/hip_bf16.h>
#include <stdint.h>

// out = X @ W^T + 0.01*(|X| @ |W|^T) - 1e-6, all 4096x4096, fp32 in/out.
// Convert X,W to bf16 in d_ws, then dual-accumulator MFMA GEMM:
// abs fragments made by ANDing sign bits off the staged bf16 fragments.
// R3: double-buffered LDS 2-phase pipeline (prefetch tile t+1 during
// compute of tile t; single __syncthreads per tile). Fragment math,
// swizzle, epilogue identical to the verified R1 kernel.

#define NDIM 4096
#define KDIM 4096
#define NT (KDIM / 64)

typedef __attribute__((ext_vector_type(8))) __bf16 bf16x8;
typedef __attribute__((ext_vector_type(8))) unsigned short u16x8;
typedef __attribute__((ext_vector_type(4))) float f32x4;
typedef __attribute__((ext_vector_type(4))) int i32x4;

// ---------------- fp32 -> bf16 (RNE), 8 elems/thread ----------------
__global__ __launch_bounds__(256) void f32_to_bf16_kernel(
    const float* __restrict__ src, unsigned short* __restrict__ dst, int n8) {
  int i = blockIdx.x * 256 + threadIdx.x;
  if (i >= n8) return;
  const float4* sp = reinterpret_cast<const float4*>(src) + (size_t)i * 2;
  float4 a = sp[0];
  float4 b = sp[1];
  float v[8] = {a.x, a.y, a.z, a.w, b.x, b.y, b.z, b.w};
  u16x8 r;
#pragma unroll
  for (int j = 0; j < 8; ++j) {
    uint32_t u = __builtin_bit_cast(uint32_t, v[j]);
    u += 0x7FFFu + ((u >> 16) & 1u);  // round-to-nearest-even
    r[j] = (unsigned short)(u >> 16);
  }
  *reinterpret_cast<u16x8*>(dst + (size_t)i * 8) = r;
}

// ---------------- dual GEMM: tile 128x128, BK=64, 8 waves (2Mx4N) ----------
// LDS rows are 128B: 16B-granule XOR swizzle g^(row&7) via pre-swizzled
// global source (global_load_lds dest stays linear); reads apply same XOR.
__global__ __launch_bounds__(512, 2) void gemm_dual_kernel(
    const unsigned short* __restrict__ Xb, const unsigned short* __restrict__ Wb,
    float* __restrict__ out) {
  __shared__ alignas(16) unsigned short As[2][128 * 64];
  __shared__ alignas(16) unsigned short Bs[2][128 * 64];

  const int tid = threadIdx.x;
  const int l = tid & 63;
  const int w = tid >> 6;  // wave 0..7
  const int wr = w >> 2;   // 0..1  (M)
  const int wc = w & 3;    // 0..3  (N)

  const int bm = blockIdx.x & 31;
  const int bn = blockIdx.x >> 5;
  const int row0 = bm << 7;
  const int col0 = bn << 7;

  // --- staging: wave w covers 8 rows per 1KB chunk; chunk-row = l>>3 ---
  const int rsub = (w << 3) + (l >> 3);   // 0..63
  const int gsrc = (l & 7) ^ (l >> 3);    // swizzled source granule (16B)
  const unsigned short* aSrc = Xb + (size_t)(row0 + rsub) * KDIM + gsrc * 8;
  const unsigned short* bSrc = Wb + (size_t)(col0 + rsub) * KDIM + gsrc * 8;
  const int ldsOff = w * 512;  // wave-uniform LDS element offset (1KB chunks)

  // --- fragment read offsets (elements), 16x16x32 layout (R1-verified) ---
  const int lr = l & 15;
  const int kq = l >> 4;              // 0..3
  const int g0 = kq ^ (lr & 7);       // swizzled granule for kk=0
  int aRow[4], bRow[2];
#pragma unroll
  for (int fm = 0; fm < 4; ++fm) aRow[fm] = ((wr << 6) + (fm << 4) + lr) * 64;
#pragma unroll
  for (int fn = 0; fn < 2; ++fn) bRow[fn] = ((wc << 5) + (fn << 4) + lr) * 64;
  const int gE0 = g0 * 8;
  const int gE1 = (g0 ^ 4) * 8;  // kk=1: granule = (kq+4)^(lr&7) = g0^4

  f32x4 accS[4][2], accA[4][2];
#pragma unroll
  for (int i = 0; i < 4; ++i)
#pragma unroll
    for (int j = 0; j < 2; ++j) {
      accS[i][j] = (f32x4)0.0f;
      accA[i][j] = (f32x4)0.0f;
    }

#define STAGE(buf, kt)                                                          \
  do {                                                                          \
    const unsigned short* ap_ = aSrc + (kt) * 64;                               \
    const unsigned short* bp_ = bSrc + (kt) * 64;                               \
    unsigned short* ad_ = &As[buf][ldsOff];                                     \
    unsigned short* bd_ = &Bs[buf][ldsOff];                                     \
    __builtin_amdgcn_global_load_lds(                                           \
        (const __attribute__((address_space(1))) void*)ap_,                     \
        (__attribute__((address_space(3))) void*)ad_, 16, 0, 0);                \
    __builtin_amdgcn_global_load_lds(                                           \
        (const __attribute__((address_space(1))) void*)(ap_ + (size_t)64 * KDIM), \
        (__attribute__((address_space(3))) void*)(ad_ + 4096), 16, 0, 0);       \
    __builtin_amdgcn_global_load_lds(                                           \
        (const __attribute__((address_space(1))) void*)bp_,                     \
        (__attribute__((address_space(3))) void*)bd_, 16, 0, 0);                \
    __builtin_amdgcn_global_load_lds(                                           \
        (const __attribute__((address_space(1))) void*)(bp_ + (size_t)64 * KDIM), \
        (__attribute__((address_space(3))) void*)(bd_ + 4096), 16, 0, 0);       \
  } while (0)

  STAGE(0, 0);
  __syncthreads();

  int cur = 0;
  for (int kt = 0; kt < NT; ++kt) {
    if (kt + 1 < NT) STAGE(cur ^ 1, kt + 1);  // prefetch flies during compute

    const unsigned short* Ab = As[cur];
    const unsigned short* Bb = Bs[cur];
#pragma unroll
    for (int kk = 0; kk < 2; ++kk) {
      const int gE = (kk == 0) ? gE0 : gE1;
      i32x4 aR[4], bR[2], aAbs[4], bAbs[2];
#pragma unroll
      for (int fm = 0; fm < 4; ++fm) {
        aR[fm] = *reinterpret_cast<const i32x4*>(Ab + aRow[fm] + gE);
        aAbs[fm] = aR[fm] & 0x7FFF7FFF;
      }
#pragma unroll
      for (int fn = 0; fn < 2; ++fn) {
        bR[fn] = *reinterpret_cast<const i32x4*>(Bb + bRow[fn] + gE);
        bAbs[fn] = bR[fn] & 0x7FFF7FFF;
      }
#pragma unroll
      for (int fm = 0; fm < 4; ++fm)
#pragma unroll
        for (int fn = 0; fn < 2; ++fn) {
          accS[fm][fn] = __builtin_amdgcn_mfma_f32_16x16x32_bf16(
              __builtin_bit_cast(bf16x8, aR[fm]), __builtin_bit_cast(bf16x8, bR[fn]),
              accS[fm][fn], 0, 0, 0);
          accA[fm][fn] = __builtin_amdgcn_mfma_f32_16x16x32_bf16(
              __builtin_bit_cast(bf16x8, aAbs[fm]), __builtin_bit_cast(bf16x8, bAbs[fn]),
              accA[fm][fn], 0, 0, 0);
        }
    }
    __syncthreads();  // drains prefetch (vmcnt 0) + protects buf reuse
    cur ^= 1;
  }
#undef STAGE

  // --- epilogue: C/D layout col=lane&15, row=(lane>>4)*4+j (m89-verified) ---
  const int orow = row0 + (wr << 6) + kq * 4;
  const int ocol = col0 + (wc << 5) + lr;
#pragma unroll
  for (int fm = 0; fm < 4; ++fm)
#pragma unroll
    for (int fn = 0; fn < 2; ++fn)
#pragma unroll
      for (int j = 0; j < 4; ++j) {
        int r = orow + fm * 16 + j;
        int c = ocol + fn * 16;
        out[(size_t)r * NDIM + c] = accS[fm][fn][j] + 0.01f * accA[fm][fn][j] - 1e-6f;
      }
}

extern "C" void kernel_launch(void* const* d_in, const int* in_sizes, int n_in,
                              void* d_out, int out_size, void* d_ws, size_t ws_size,
                              hipStream_t stream) {
  const float* X = (const float*)d_in[0];
  const float* W = (const float*)d_in[1];
  float* out = (float*)d_out;
  unsigned short* Xb = (unsigned short*)d_ws;
  unsigned short* Wb = Xb + (size_t)NDIM * KDIM;

  const int n8 = (NDIM * KDIM) / 8;  // 2,097,152
  const int cblocks = n8 / 256;      // 8,192
  hipLaunchKernelGGL(f32_to_bf16_kernel, dim3(cblocks), dim3(256), 0, stream, X, Xb, n8);
  hipLaunchKernelGGL(f32_to_bf16_kernel, dim3(cblocks), dim3(256), 0, stream, W, Wb, n8);
  hipLaunchKernelGGL(gemm_dual_kernel, dim3((NDIM / 128) * (NDIM / 128)), dim3(512), 0,
                     stream, Xb, Wb, out);
}